// Round 3
// baseline (238.511 us; speedup 1.0000x reference)
//
#include <hip/hip_runtime.h>

// Loss = L1*sl1(1,iou) + L2*sl1(t[:4],p[:4]) + L3*sl1(t[12],p[12]) + 0.5*L4*sl1(t[4:12],p[4:12])
// shapes: (B=256, N=8192, F=13) fp32. B*N = 2^21 rows.
//
// Round-2 post-mortem: counted-vmcnt per-wave pipelining of global_load_lds
// changed NOTHING vs the barrier-drained round-0 schedule (83.1 vs 83.4 us,
// 1.3 TB/s HBM, VALU 10%). Two different schedules, identical duration =>
// throughput cap in the shared element: the LDS-DMA return path of
// global_load_lds appears to have a shallow per-CU queue (~8 x 1 KB at
// ~1200 cy mixed L3/HBM latency = the measured ~2.6 TB/s effective,
// independent of pipeline depth).
//
// This version stages through VGPRs instead (T14 reg-staging): plain float4
// loads (the 6.3 TB/s m13 path, vmcnt up to 63 outstanding per wave) +
// ds_write_b128 into the same LDS layout. Compute is unchanged. Per-wave
// pipeline: 2 groups in registers in flight, 2-deep LDS ring, no
// __syncthreads in the main loop; compiler inserts the counted vmcnt waits
// from VGPR dependencies.
//
// 512 blocks * 4 waves = 2048 waves; 32768 groups => exactly 16 groups/wave.
// LDS: 4 waves * 2 bufs * 2 tensors * 3328 B = 53,248 B (< 64 KiB limit).

#define NGRP   32768            // (B*N)/64 row-groups
#define GBYTES 3328             // bytes per tensor per group (64 rows * 52 B)
#define GFLOAT 832              // floats per tensor per group
#define NBLK   512              // 2 blocks/CU * 256 CU
#define NWAVE  (NBLK * 4)       // 2048 waves
#define GPW    (NGRP / NWAVE)   // 16 groups per wave (even — 2-step loop relies on it)

struct Grp {                    // one group's slice for one lane: 26 dwords
    float4 t[3]; float tt;
    float4 p[3]; float pt;
};

__device__ __forceinline__ float sl1(float d) {
    d = fabsf(d);
    return d < 1.0f ? 0.5f * d * d : d - 0.5f;
}

__device__ __forceinline__ void load_grp(const float* __restrict__ T,
                                         const float* __restrict__ P,
                                         long long g, int lane, Grp& r) {
    const char* tb = (const char*)T + g * GBYTES;
    const char* pb = (const char*)P + g * GBYTES;
#pragma unroll
    for (int s = 0; s < 3; ++s) {
        r.t[s] = *(const float4*)(tb + s * 1024 + lane * 16);
        r.p[s] = *(const float4*)(pb + s * 1024 + lane * 16);
    }
    r.tt = *(const float*)(tb + 3072 + lane * 4);
    r.pt = *(const float*)(pb + 3072 + lane * 4);
}

__device__ __forceinline__ void write_grp(float* lt, float* lp, int lane, const Grp& r) {
#pragma unroll
    for (int s = 0; s < 3; ++s) {
        *(float4*)((char*)lt + s * 1024 + lane * 16) = r.t[s];
        *(float4*)((char*)lp + s * 1024 + lane * 16) = r.p[s];
    }
    lt[768 + lane] = r.tt;
    lp[768 + lane] = r.pt;
}

__device__ __forceinline__ float compute_grp(const float* t, const float* p, int lane) {
    const int rb = lane * 13;

    float t0 = t[rb + 0], t1 = t[rb + 1], t2 = t[rb + 2], t3 = t[rb + 3];
    float p0 = p[rb + 0], p1 = p[rb + 1], p2 = p[rb + 2], p3 = p[rb + 3];

    float s2 = sl1(t0 - p0) + sl1(t1 - p1) + sl1(t2 - p2) + sl1(t3 - p3);

    float s4 = 0.0f;
#pragma unroll
    for (int f = 4; f < 12; ++f) s4 += sl1(t[rb + f] - p[rb + f]);

    float s3 = sl1(t[rb + 12] - p[rb + 12]);

    float xx1 = fmaxf(t0, p0);
    float yy1 = fmaxf(t1, p1);
    float xx2 = fminf(t2, p2);
    float yy2 = fminf(t3, p3);
    float w  = fmaxf(xx2 - xx1, 0.0f);
    float h  = fmaxf(yy2 - yy1, 0.0f);
    float inter = w * h;
    float a1 = (t2 - t0) * (t3 - t1);
    float a2 = (p2 - p0) * (p3 - p1);
    float iou = inter / (a1 + a2 - inter + 1e-7f);
    float s1 = sl1(1.0f - iou);

    // Exact power-of-two mean weights: B*N = 2^21.
    constexpr float W1 = 1.0f / 2097152.0f;    // 1/(B*N)
    constexpr float W2 = 1.0f / 8388608.0f;    // 1/(B*N*4)
    constexpr float W3 = 1.0f / 2097152.0f;    // 1/(B*N)
    constexpr float W4 = 1.0f / 33554432.0f;   // 0.5/(B*N*8)
    return W1 * s1 + W2 * s2 + W3 * s3 + W4 * s4;
}

__global__ __launch_bounds__(256) void loss_stage1(const float* __restrict__ T,
                                                   const float* __restrict__ P,
                                                   float* __restrict__ partial) {
    // [wave][buf][tensor][floats] — each wave touches only its own slice.
    __shared__ __align__(16) float lds[4][2][2][GFLOAT];   // 53,248 B
    __shared__ float wred[4];

    const int tid  = threadIdx.x;
    const int lane = tid & 63;
    const int wv   = tid >> 6;
    const long long wid = blockIdx.x * 4 + wv;   // global wave id

    float* lt0 = &lds[wv][0][0][0];
    float* lp0 = &lds[wv][0][1][0];
    float* lt1 = &lds[wv][1][0][0];
    float* lp1 = &lds[wv][1][1][0];

    // Prologue: issue groups 0,1 into regs; write g0 to lds0 (compiler waits
    // vmcnt for r0 only — r1's 8 loads stay outstanding); issue g2 into r0.
    Grp r0, r1;
    load_grp(T, P, wid, lane, r0);
    load_grp(T, P, wid + NWAVE, lane, r1);
    write_grp(lt0, lp0, lane, r0);
    load_grp(T, P, wid + 2 * NWAVE, lane, r0);

    float acc = 0.0f;

    // 2-step software pipeline (GPW even, fully static indexing — rule #20):
    //   even step i  : compute lds0(g i)  | write lds1 <- r1(g i+1) | load r1 <- g i+3
    //   odd  step i+1: compute lds1(g i+1)| write lds0 <- r0(g i+2) | load r0 <- g i+4
    for (int i = 0; i < GPW; i += 2) {
        asm volatile("s_waitcnt lgkmcnt(0)" ::: "memory");   // lds0 write landed
        __builtin_amdgcn_sched_barrier(0);
        acc += compute_grp(lt0, lp0, lane);
        write_grp(lt1, lp1, lane, r1);                        // g(i+1); vmcnt by reg-dep
        if (i + 3 < GPW) load_grp(T, P, wid + (long long)(i + 3) * NWAVE, lane, r1);

        asm volatile("s_waitcnt lgkmcnt(0)" ::: "memory");   // lds1 write landed
        __builtin_amdgcn_sched_barrier(0);
        acc += compute_grp(lt1, lp1, lane);
        if (i + 2 < GPW) write_grp(lt0, lp0, lane, r0);       // g(i+2)
        if (i + 4 < GPW) load_grp(T, P, wid + (long long)(i + 4) * NWAVE, lane, r0);
    }

    // Block reduction: wave64 shuffle -> 4-wave LDS -> one partial per block.
#pragma unroll
    for (int off = 32; off > 0; off >>= 1)
        acc += __shfl_down(acc, off, 64);
    if (lane == 0) wred[wv] = acc;
    __syncthreads();
    if (tid == 0)
        partial[blockIdx.x] = wred[0] + wred[1] + wred[2] + wred[3];
}

__global__ __launch_bounds__(256) void loss_stage2(const float* __restrict__ partial,
                                                   float* __restrict__ out) {
    __shared__ float wred[4];
    const int tid = threadIdx.x;
    float a = 0.0f;
    for (int i = tid; i < NBLK; i += 256) a += partial[i];
#pragma unroll
    for (int off = 32; off > 0; off >>= 1)
        a += __shfl_down(a, off, 64);
    if ((tid & 63) == 0) wred[tid >> 6] = a;
    __syncthreads();
    if (tid == 0) out[0] = wred[0] + wred[1] + wred[2] + wred[3];
}

extern "C" void kernel_launch(void* const* d_in, const int* in_sizes, int n_in,
                              void* d_out, int out_size, void* d_ws, size_t ws_size,
                              hipStream_t stream) {
    const float* targets = (const float*)d_in[0];
    const float* preds   = (const float*)d_in[1];
    float* out     = (float*)d_out;
    float* partial = (float*)d_ws;   // NBLK floats of scratch

    loss_stage1<<<NBLK, 256, 0, stream>>>(targets, preds, partial);
    loss_stage2<<<1, 256, 0, stream>>>(partial, out);
}